// Round 1
// baseline (2348.026 us; speedup 1.0000x reference)
//
#include <hip/hip_runtime.h>
#include <hip/hip_bf16.h>
#include <cstdint>

#define NEG (-1e30f)
#define VSZ 256          // vocab size (fixed for this problem)
#define LMAX 448         // >= L = 2*S+1 = 401, multiple of 64

// ---------------------------------------------------------------------------
// Kernel A: per-(b,t) logsumexp over V=256. One wave per row.
// ---------------------------------------------------------------------------
__global__ __launch_bounds__(256) void lse_kernel(const float* __restrict__ logits,
                                                  float* __restrict__ lse,
                                                  int nrows) {
    int row = blockIdx.x * 4 + (threadIdx.x >> 6);
    if (row >= nrows) return;
    int lane = threadIdx.x & 63;
    const float4* p = (const float4*)(logits + (size_t)row * VSZ);
    float4 x = p[lane];                       // 64 lanes * 16B = full 1KB row
    float m = fmaxf(fmaxf(x.x, x.y), fmaxf(x.z, x.w));
    #pragma unroll
    for (int off = 32; off; off >>= 1) m = fmaxf(m, __shfl_xor(m, off, 64));
    float s = __expf(x.x - m) + __expf(x.y - m) + __expf(x.z - m) + __expf(x.w - m);
    #pragma unroll
    for (int off = 32; off; off >>= 1) s += __shfl_xor(s, off, 64);
    if (lane == 0) lse[row] = m + __logf(s);
}

// ---------------------------------------------------------------------------
// Kernel B: sequential CTC alpha recursion. One block per batch element.
// Thread s owns extended state s (s < L). Alpha double-buffered in LDS ->
// exactly one barrier per time step. Gathered logit + lse prefetched with
// distance 2 to hide global latency.
// ---------------------------------------------------------------------------
__device__ __forceinline__ float lae(float a, float b) {
    float mx = fmaxf(a, b);
    float mn = fminf(a, b);
    return mx + log1pf(__expf(mn - mx));
}

__global__ __launch_bounds__(LMAX, 1) void ctc_scan(const float* __restrict__ logits,
                                                    const int* __restrict__ targets,
                                                    const int* __restrict__ llen_p,
                                                    const int* __restrict__ tlen_p,
                                                    const float* __restrict__ lse,
                                                    float* __restrict__ out,
                                                    int T, int S) {
    const int b   = blockIdx.x;
    const int L   = 2 * S + 1;
    const int tid = threadIdx.x;

    __shared__ float alpha[2][LMAX + 8];

    const int len = llen_p[b];                    // 1 <= len <= T
    const float* __restrict__ lgb  = logits + (size_t)b * T * VSZ;
    const float* __restrict__ lseb = lse + (size_t)b * T;

    // per-state label + skip flag (registers)
    int  lab  = 0;
    bool skip = false;
    if (tid < L) {
        if (tid & 1) {
            int j = tid >> 1;
            lab = targets[b * S + j];
            int prev = (j >= 1) ? targets[b * S + j - 1] : -1;
            skip = (lab != prev);                 // lab != 0 always (labels in [1,V))
        }
        alpha[0][tid] = (tid == 0) ? 0.0f : NEG;
    }
    __syncthreads();

    // prefetch t=0, t=1
    float val0 = 0.f, val1 = 0.f, lse0 = 0.f, lse1 = 0.f;
    if (tid < L) val0 = lgb[lab];
    lse0 = lseb[0];
    if (len > 1) {
        if (tid < L) val1 = lgb[VSZ + lab];
        lse1 = lseb[1];
    }

    for (int t = 0; t < len; ++t) {
        const int cur = t & 1, nxt = cur ^ 1;
        // prefetch t+2
        float val2 = 0.f, lse2 = 0.f;
        if (t + 2 < len) {
            if (tid < L) val2 = lgb[(size_t)(t + 2) * VSZ + lab];
            lse2 = lseb[t + 2];
        }
        if (tid < L) {
            float a0 = alpha[cur][tid];
            float a1 = (tid >= 1) ? alpha[cur][tid - 1] : NEG;
            float a2 = (skip && tid >= 2) ? alpha[cur][tid - 2] : NEG;
            float nw = lae(lae(a0, a1), a2) + (val0 - lse0);
            alpha[nxt][tid] = nw;
        }
        __syncthreads();
        val0 = val1; lse0 = lse1;
        val1 = val2; lse1 = lse2;
    }

    if (tid == 0) {
        int tl = tlen_p[b];
        const float* af = alpha[len & 1];
        float l1 = af[2 * tl - 1];
        float l2 = af[2 * tl];
        out[b] = -lae(l1, l2);
    }
}

// ---------------------------------------------------------------------------
extern "C" void kernel_launch(void* const* d_in, const int* in_sizes, int n_in,
                              void* d_out, int out_size, void* d_ws, size_t ws_size,
                              hipStream_t stream) {
    const float* logits  = (const float*)d_in[0];
    const int*   targets = (const int*)d_in[1];
    const int*   llen    = (const int*)d_in[2];
    const int*   tlen    = (const int*)d_in[3];
    float*       out     = (float*)d_out;

    const int B = in_sizes[2];
    const int S = in_sizes[1] / B;
    const int T = in_sizes[0] / (B * VSZ);

    float* lse = (float*)d_ws;                 // B*T floats (512 KB)

    const int nrows = B * T;
    lse_kernel<<<(nrows + 3) / 4, 256, 0, stream>>>(logits, lse, nrows);
    ctc_scan<<<B, LMAX, 0, stream>>>(logits, targets, llen, tlen, lse, out, T, S);
}

// Round 2
// 754.175 us; speedup vs baseline: 3.1134x; 3.1134x over previous
//
#include <hip/hip_runtime.h>
#include <hip/hip_bf16.h>
#include <cstdint>

#define NEG  (-1e30f)
#define VSZ  256      // vocab size (fixed for this problem)
#define TCAP 2048     // >= T = 2000
#define NTHR 256      // threads in ctc_scan; thread i owns states 2i, 2i+1

// ---------------------------------------------------------------------------
// Kernel A: per-(b,t) logsumexp over V=256. One wave per row.
// ---------------------------------------------------------------------------
__global__ __launch_bounds__(256) void lse_kernel(const float* __restrict__ logits,
                                                  float* __restrict__ lse,
                                                  int nrows) {
    int row = blockIdx.x * 4 + (threadIdx.x >> 6);
    if (row >= nrows) return;
    int lane = threadIdx.x & 63;
    const float4* p = (const float4*)(logits + (size_t)row * VSZ);
    float4 x = p[lane];                       // 64 lanes * 16B = full 1KB row
    float m = fmaxf(fmaxf(x.x, x.y), fmaxf(x.z, x.w));
    #pragma unroll
    for (int off = 32; off; off >>= 1) m = fmaxf(m, __shfl_xor(m, off, 64));
    float s = __expf(x.x - m) + __expf(x.y - m) + __expf(x.z - m) + __expf(x.w - m);
    #pragma unroll
    for (int off = 32; off; off >>= 1) s += __shfl_xor(s, off, 64);
    if (lane == 0) lse[row] = m + __logf(s);
}

// ---------------------------------------------------------------------------
// log-add-exp on raw (unnormalized) values
// ---------------------------------------------------------------------------
__device__ __forceinline__ float lae(float a, float b) {
    float mx = fmaxf(a, b);
    float mn = fminf(a, b);
    return mx + __logf(1.0f + __expf(mn - mx));
}

// barrier that drains ONLY lgkmcnt (LDS/SMEM) — global prefetch loads stay in
// flight across it (they're thread-private, no cross-thread visibility needed)
__device__ __forceinline__ void barrier_lgkm() {
    __asm__ volatile("s_waitcnt lgkmcnt(0)\n\ts_barrier" ::: "memory");
}

// ---------------------------------------------------------------------------
// Kernel B: sequential CTC alpha recursion on RAW logits (lse subtracted at
// the end via the log-semiring shift identity). One block per batch element.
// Thread i owns extended states 2i (blank) and 2i+1 (label) in REGISTERS.
// Only odd states are read by a neighbor -> one LDS write + one LDS read +
// one lgkm-only barrier per time step. Blank column pre-staged in LDS;
// label gather prefetched distance 3.
// ---------------------------------------------------------------------------
__global__ __launch_bounds__(NTHR, 1) void ctc_scan(const float* __restrict__ logits,
                                                    const int* __restrict__ targets,
                                                    const int* __restrict__ llen_p,
                                                    const int* __restrict__ tlen_p,
                                                    const float* __restrict__ lse,
                                                    float* __restrict__ out,
                                                    int T, int S) {
    const int b = blockIdx.x;
    const int i = threadIdx.x;
    const int len = llen_p[b];                   // 1 <= len <= T

    __shared__ float blankv[TCAP];               // staged logits[b, t, 0]
    __shared__ float abuf[2][NTHR + 2];          // double-buffered odd states
    __shared__ float wsum[NTHR / 64];

    const float* __restrict__ lgb  = logits + (size_t)b * T * VSZ;
    const float* __restrict__ lseb = lse + (size_t)b * T;

    // per-thread label + skip flag (thread i -> target index i)
    int  lab  = 0;                               // threads >= S read blank col (harmless)
    bool skip = false;
    if (i < S) {
        lab = targets[b * S + i];
        int prev = (i >= 1) ? targets[b * S + i - 1] : -1;
        skip = (lab != prev);                    // lab != 0 always (labels in [1,V))
    }

    // stage the blank column (uniform-address -> would be SMEM in-loop)
    for (int t = i; t < len; t += NTHR) blankv[t] = lgb[(size_t)t * VSZ];
    if (i < 2) abuf[i][0] = NEG;                 // left halo for thread 0
    __syncthreads();

    float aEven = (i == 0) ? 0.0f : NEG;         // alpha0: state 0 = 0, rest NEG
    float aOdd  = NEG;

    // prefetch label logits, distance 3 (clamped addresses, always in-bounds)
    const int lm1 = len - 1;
    float v0 = lgb[(size_t)lab];                               // t = 0
    float v1 = lgb[(size_t)min(1, lm1) * VSZ + lab];
    float v2 = lgb[(size_t)min(2, lm1) * VSZ + lab];

    for (int t = 0; t < len; ++t) {
        float v3 = lgb[(size_t)min(t + 3, lm1) * VSZ + lab];   // prefetch t+3
        float bl = blankv[t];
        abuf[t & 1][i + 1] = aOdd;               // publish OLD odd state
        barrier_lgkm();
        float nb = abuf[t & 1][i];               // old alpha[2i-1] from neighbor
        float ne = lae(aEven, nb) + bl;                              // state 2i
        float no = lae(lae(aOdd, aEven), skip ? nb : NEG) + v0;      // state 2i+1
        aEven = ne; aOdd = no;
        v0 = v1; v1 = v2; v2 = v3;
    }

    // final alphas -> LDS (reuse blankv; all in-loop reads of it are done)
    blankv[2 * i]     = aEven;
    blankv[2 * i + 1] = aOdd;

    // sum of lse[b, 0..len) (the shift correction), block reduction
    float part = 0.f;
    for (int t = i; t < len; t += NTHR) part += lseb[t];
    #pragma unroll
    for (int off = 32; off; off >>= 1) part += __shfl_xor(part, off, 64);
    if ((i & 63) == 0) wsum[i >> 6] = part;
    __syncthreads();

    if (i == 0) {
        int tl = tlen_p[b];
        float s = wsum[0] + wsum[1] + wsum[2] + wsum[3];
        out[b] = s - lae(blankv[2 * tl - 1], blankv[2 * tl]);
    }
}

// ---------------------------------------------------------------------------
extern "C" void kernel_launch(void* const* d_in, const int* in_sizes, int n_in,
                              void* d_out, int out_size, void* d_ws, size_t ws_size,
                              hipStream_t stream) {
    const float* logits  = (const float*)d_in[0];
    const int*   targets = (const int*)d_in[1];
    const int*   llen    = (const int*)d_in[2];
    const int*   tlen    = (const int*)d_in[3];
    float*       out     = (float*)d_out;

    const int B = in_sizes[2];
    const int S = in_sizes[1] / B;
    const int T = in_sizes[0] / (B * VSZ);

    float* lse = (float*)d_ws;                 // B*T floats (512 KB)

    const int nrows = B * T;
    lse_kernel<<<(nrows + 3) / 4, 256, 0, stream>>>(logits, lse, nrows);
    ctc_scan<<<B, NTHR, 0, stream>>>(logits, targets, llen, tlen, lse, out, T, S);
}

// Round 3
// 641.432 us; speedup vs baseline: 3.6606x; 1.1758x over previous
//
#include <hip/hip_runtime.h>
#include <hip/hip_bf16.h>
#include <cstdint>

#define NEG   (-1e30f)
#define VSZ   256      // vocab size (fixed for this problem)
#define TCAP  2048     // >= T = 2000
#define NTHR  256      // scan threads; thread i owns states 2i, 2i+1
#define LOG2E 1.4426950408889634f
#define LN2   0.6931471805599453f

// native base-2 exp/log (v_exp_f32 / v_log_f32)
__device__ __forceinline__ float fexp2(float x) { return __builtin_amdgcn_exp2f(x); }
__device__ __forceinline__ float flog2(float x) { return __builtin_amdgcn_logf(x); }

__device__ __forceinline__ float lae2b(float a, float b) {
    float m = fmaxf(a, b);
    return m + flog2(fexp2(a - m) + fexp2(b - m));
}
__device__ __forceinline__ float lae3b(float a, float b, float c) {
    float m = fmaxf(fmaxf(a, b), c);           // v_max3
    return m + flog2(fexp2(a - m) + fexp2(b - m) + fexp2(c - m));
}

// barrier draining ONLY lgkmcnt — global prefetch loads stay in flight
__device__ __forceinline__ void barrier_lgkm() {
    __asm__ volatile("s_waitcnt lgkmcnt(0)\n\ts_barrier" ::: "memory");
}

// ---------------------------------------------------------------------------
// Prep: per (b,t) row -> lse; write gl[row][c] = (logit[lab[c]] - lse)*log2e
// (c = target index, clamped) and bl[row] = (blank logit - lse)*log2e.
// One wave per row; row staged in LDS for the label gather.
// ---------------------------------------------------------------------------
__global__ __launch_bounds__(256) void prep_kernel(const float* __restrict__ logits,
                                                   const int* __restrict__ targets,
                                                   float* __restrict__ gl,
                                                   float* __restrict__ bl,
                                                   int nrows, int T, int S) {
    int row = blockIdx.x * 4 + (threadIdx.x >> 6);
    if (row >= nrows) return;
    int lane = threadIdx.x & 63;
    int wv   = threadIdx.x >> 6;
    __shared__ float ldsrow[4][VSZ];

    const float4* p = (const float4*)(logits + (size_t)row * VSZ);
    float4 x = p[lane];
    ((float4*)&ldsrow[wv][0])[lane] = x;

    float m = fmaxf(fmaxf(x.x, x.y), fmaxf(x.z, x.w));
    #pragma unroll
    for (int off = 32; off; off >>= 1) m = fmaxf(m, __shfl_xor(m, off, 64));
    float s = __expf(x.x - m) + __expf(x.y - m) + __expf(x.z - m) + __expf(x.w - m);
    #pragma unroll
    for (int off = 32; off; off >>= 1) s += __shfl_xor(s, off, 64);
    float lse = m + __logf(s);

    int b = row / T;
    const int* tg = targets + (size_t)b * S;
    float* glr = gl + (size_t)row * VSZ;
    #pragma unroll
    for (int k = 0; k < 4; ++k) {
        int c = lane + 64 * k;
        int lab = tg[min(c, S - 1)];           // cached (targets tiny)
        glr[c] = (ldsrow[wv][lab] - lse) * LOG2E;
    }
    if (lane == 0) bl[row] = (x.x - lse) * LOG2E;
}

// ---------------------------------------------------------------------------
// Scan v3: 4 time steps per barrier. Thread i holds window W[0..9] =
// states [2i-8 .. 2i+1]; W[8],W[9] are its own states. Per period:
// publish own 2 states -> lgkm barrier -> read 8 halo states -> 4 local
// micro-steps (descending m uses only old lower entries). Coalesced gather
// values prefetched 2 periods ahead; blank column staged in LDS.
// ---------------------------------------------------------------------------
__global__ __launch_bounds__(NTHR, 1) void ctc_scan4(const float* __restrict__ gl,
                                                     const float* __restrict__ bl,
                                                     const int* __restrict__ targets,
                                                     const int* __restrict__ llen_p,
                                                     const int* __restrict__ tlen_p,
                                                     float* __restrict__ out,
                                                     int T, int S) {
    const int b = blockIdx.x;
    const int i = threadIdx.x;
    const int len = llen_p[b];

    __shared__ float blankv[TCAP];
    __shared__ int   tgts[NTHR];
    __shared__ float ex[2][8 + 2 * NTHR];
    __shared__ float fin[2 * NTHR];

    const float* __restrict__ glb = gl + (size_t)b * T * VSZ;
    const float* __restrict__ blb = bl + (size_t)b * T;

    for (int t = i; t < len; t += NTHR) blankv[t] = blb[t];
    tgts[i] = targets[(size_t)b * S + min(i, S - 1)];
    if (i < 8) { ex[0][i] = NEG; ex[1][i] = NEG; }
    __syncthreads();

    // skip flags for odd states of threads i-3..i (window slots 3,5,7,9)
    bool sk[4];
    #pragma unroll
    for (int d = 0; d < 4; ++d) {
        int j = i - 3 + d;
        sk[d] = (j <= 0) ? true : (tgts[j] != tgts[j - 1]);
    }

    float W[10];
    W[8] = (i == 0) ? 0.0f : NEG;
    W[9] = NEG;

    const int lm1 = len - 1;
    const int i0 = max(i - 3, 0), i1 = max(i - 2, 0), i2 = max(i - 1, 0);

    // gather-value set for period starting at t4 (multiple of 4):
    // g[0..3] = t  : cols i-3,i-2,i-1,i ; g[4..6] = t+1 : i-2,i-1,i
    // g[7..8] = t+2: i-1,i              ; g[9]    = t+3 : i
    auto loadset = [&](int t4, float* g, float4& cb) {
        int ta = min(t4, lm1), tb = min(t4 + 1, lm1);
        int tc = min(t4 + 2, lm1), td = min(t4 + 3, lm1);
        const float* pa = glb + (size_t)ta * VSZ;
        const float* pb = glb + (size_t)tb * VSZ;
        const float* pc = glb + (size_t)tc * VSZ;
        const float* pd = glb + (size_t)td * VSZ;
        g[0] = pa[i0]; g[1] = pa[i1]; g[2] = pa[i2]; g[3] = pa[i];
        g[4] = pb[i1]; g[5] = pb[i2]; g[6] = pb[i];
        g[7] = pc[i2]; g[8] = pc[i];
        g[9] = pd[i];
        cb = *(const float4*)&blankv[t4];      // may read past len: unused
    };

    float ga[10], gb[10], gc[10];
    float4 ca, cb4, cc;
    const int P = (len + 3) >> 2;
    loadset(0, ga, ca);
    loadset(4, gb, cb4);                       // clamped if len small

#define EV(m, BL)  W[m] = lae2b(W[m], W[m - 1]) + (BL)
#define OD(m, GV)  W[m] = lae3b(W[m], W[m - 1], sk[((m) - 3) / 2] ? W[m - 2] : NEG) + (GV)

    for (int p = 0; p < P; ++p) {
        const int t   = 4 * p;
        const int par = p & 1;
        *(float2*)&ex[par][8 + 2 * i] = make_float2(W[8], W[9]);
        barrier_lgkm();
        #pragma unroll
        for (int r = 0; r < 8; r += 2) {
            float2 h = *(const float2*)&ex[par][2 * i + r];
            W[r] = h.x; W[r + 1] = h.y;
        }
        loadset(t + 8, gc, cc);                // prefetch distance 2

        // micro-step j=0 (time t)
        if (t < len) {
            OD(9, ga[3]); EV(8, ca.x); OD(7, ga[2]); EV(6, ca.x);
            OD(5, ga[1]); EV(4, ca.x); OD(3, ga[0]); EV(2, ca.x);
        }
        if (t + 1 < len) {
            OD(9, ga[6]); EV(8, ca.y); OD(7, ga[5]); EV(6, ca.y);
            OD(5, ga[4]); EV(4, ca.y);
        }
        if (t + 2 < len) {
            OD(9, ga[8]); EV(8, ca.z); OD(7, ga[7]); EV(6, ca.z);
        }
        if (t + 3 < len) {
            OD(9, ga[9]); EV(8, ca.w);
        }
        #pragma unroll
        for (int q = 0; q < 10; ++q) { ga[q] = gb[q]; gb[q] = gc[q]; }
        ca = cb4; cb4 = cc;
    }
#undef EV
#undef OD

    fin[2 * i]     = W[8];
    fin[2 * i + 1] = W[9];
    __syncthreads();
    if (i == 0) {
        int tl = tlen_p[b];
        out[b] = -lae2b(fin[2 * tl - 1], fin[2 * tl]) * LN2;
    }
}

// ---------------------------------------------------------------------------
// Fallback path (R2) if workspace is too small for the gather matrix.
// ---------------------------------------------------------------------------
__global__ __launch_bounds__(256) void lse_kernel(const float* __restrict__ logits,
                                                  float* __restrict__ lse,
                                                  int nrows) {
    int row = blockIdx.x * 4 + (threadIdx.x >> 6);
    if (row >= nrows) return;
    int lane = threadIdx.x & 63;
    const float4* p = (const float4*)(logits + (size_t)row * VSZ);
    float4 x = p[lane];
    float m = fmaxf(fmaxf(x.x, x.y), fmaxf(x.z, x.w));
    #pragma unroll
    for (int off = 32; off; off >>= 1) m = fmaxf(m, __shfl_xor(m, off, 64));
    float s = __expf(x.x - m) + __expf(x.y - m) + __expf(x.z - m) + __expf(x.w - m);
    #pragma unroll
    for (int off = 32; off; off >>= 1) s += __shfl_xor(s, off, 64);
    if (lane == 0) lse[row] = m + __logf(s);
}

__device__ __forceinline__ float lae(float a, float b) {
    float mx = fmaxf(a, b);
    float mn = fminf(a, b);
    return mx + __logf(1.0f + __expf(mn - mx));
}

__global__ __launch_bounds__(NTHR, 1) void ctc_scan_fb(const float* __restrict__ logits,
                                                       const int* __restrict__ targets,
                                                       const int* __restrict__ llen_p,
                                                       const int* __restrict__ tlen_p,
                                                       const float* __restrict__ lse,
                                                       float* __restrict__ out,
                                                       int T, int S) {
    const int b = blockIdx.x;
    const int i = threadIdx.x;
    const int len = llen_p[b];

    __shared__ float blankv[TCAP];
    __shared__ float abuf[2][NTHR + 2];
    __shared__ float wsum[NTHR / 64];

    const float* __restrict__ lgb  = logits + (size_t)b * T * VSZ;
    const float* __restrict__ lseb = lse + (size_t)b * T;

    int  lab  = 0;
    bool skip = false;
    if (i < S) {
        lab = targets[b * S + i];
        int prev = (i >= 1) ? targets[b * S + i - 1] : -1;
        skip = (lab != prev);
    }
    for (int t = i; t < len; t += NTHR) blankv[t] = lgb[(size_t)t * VSZ];
    if (i < 2) abuf[i][0] = NEG;
    __syncthreads();

    float aEven = (i == 0) ? 0.0f : NEG;
    float aOdd  = NEG;
    const int lm1 = len - 1;
    float v0 = lgb[(size_t)lab];
    float v1 = lgb[(size_t)min(1, lm1) * VSZ + lab];
    float v2 = lgb[(size_t)min(2, lm1) * VSZ + lab];

    for (int t = 0; t < len; ++t) {
        float v3 = lgb[(size_t)min(t + 3, lm1) * VSZ + lab];
        float bl = blankv[t];
        abuf[t & 1][i + 1] = aOdd;
        barrier_lgkm();
        float nb = abuf[t & 1][i];
        float ne = lae(aEven, nb) + bl;
        float no = lae(lae(aOdd, aEven), skip ? nb : NEG) + v0;
        aEven = ne; aOdd = no;
        v0 = v1; v1 = v2; v2 = v3;
    }

    blankv[2 * i]     = aEven;
    blankv[2 * i + 1] = aOdd;
    float part = 0.f;
    for (int t = i; t < len; t += NTHR) part += lseb[t];
    #pragma unroll
    for (int off = 32; off; off >>= 1) part += __shfl_xor(part, off, 64);
    if ((i & 63) == 0) wsum[i >> 6] = part;
    __syncthreads();
    if (i == 0) {
        int tl = tlen_p[b];
        float s = wsum[0] + wsum[1] + wsum[2] + wsum[3];
        out[b] = s - lae(blankv[2 * tl - 1], blankv[2 * tl]);
    }
}

// ---------------------------------------------------------------------------
extern "C" void kernel_launch(void* const* d_in, const int* in_sizes, int n_in,
                              void* d_out, int out_size, void* d_ws, size_t ws_size,
                              hipStream_t stream) {
    const float* logits  = (const float*)d_in[0];
    const int*   targets = (const int*)d_in[1];
    const int*   llen    = (const int*)d_in[2];
    const int*   tlen    = (const int*)d_in[3];
    float*       out     = (float*)d_out;

    const int B = in_sizes[2];
    const int S = in_sizes[1] / B;
    const int T = in_sizes[0] / (B * VSZ);
    const int nrows = B * T;

    const size_t need = (size_t)nrows * VSZ * sizeof(float) + (size_t)nrows * sizeof(float);
    if (ws_size >= need) {
        float* gl = (float*)d_ws;                       // nrows * 256 floats
        float* bl = (float*)d_ws + (size_t)nrows * VSZ; // nrows floats
        prep_kernel<<<(nrows + 3) / 4, 256, 0, stream>>>(logits, targets, gl, bl, nrows, T, S);
        ctc_scan4<<<B, NTHR, 0, stream>>>(gl, bl, targets, llen, tlen, out, T, S);
    } else {
        float* lse = (float*)d_ws;                      // nrows floats
        lse_kernel<<<(nrows + 3) / 4, 256, 0, stream>>>(logits, lse, nrows);
        ctc_scan_fb<<<B, NTHR, 0, stream>>>(logits, targets, llen, tlen, lse, out, T, S);
    }
}

// Round 4
// 572.193 us; speedup vs baseline: 4.1036x; 1.1210x over previous
//
#include <hip/hip_runtime.h>
#include <hip/hip_bf16.h>
#include <cstdint>

#define NEG   (-1e30f)
#define VSZ   256      // vocab size (fixed for this problem)
#define TCAP  2048     // >= T = 2000
#define NTHR  256      // scan threads; thread i owns states 2i, 2i+1
#define LOG2E 1.4426950408889634f
#define LN2   0.6931471805599453f

// native base-2 exp/log (v_exp_f32 / v_log_f32)
__device__ __forceinline__ float fexp2(float x) { return __builtin_amdgcn_exp2f(x); }
__device__ __forceinline__ float flog2(float x) { return __builtin_amdgcn_logf(x); }

__device__ __forceinline__ float lae2b(float a, float b) {
    float m = fmaxf(a, b);
    return m + flog2(fexp2(a - m) + fexp2(b - m));
}
__device__ __forceinline__ float lae3b(float a, float b, float c) {
    float m = fmaxf(fmaxf(a, b), c);           // v_max3
    return m + flog2(fexp2(a - m) + fexp2(b - m) + fexp2(c - m));
}

// barrier draining ONLY lgkmcnt — global prefetch loads stay in flight
__device__ __forceinline__ void barrier_lgkm() {
    __asm__ volatile("s_waitcnt lgkmcnt(0)\n\ts_barrier" ::: "memory");
}

// ---------------------------------------------------------------------------
// Prep: per (b,t) row -> lse; gl[row][c] = (logit[lab[c]] - lse)*log2e,
// bl[row] = (blank logit - lse)*log2e. One wave per row, float4 stores.
// ---------------------------------------------------------------------------
__global__ __launch_bounds__(256) void prep_kernel(const float* __restrict__ logits,
                                                   const int* __restrict__ targets,
                                                   float* __restrict__ gl,
                                                   float* __restrict__ bl,
                                                   int nrows, int T, int S) {
    int row = blockIdx.x * 4 + (threadIdx.x >> 6);
    if (row >= nrows) return;
    int lane = threadIdx.x & 63;
    int wv   = threadIdx.x >> 6;
    __shared__ float ldsrow[4][VSZ];

    const float4* p = (const float4*)(logits + (size_t)row * VSZ);
    float4 x = p[lane];
    ((float4*)&ldsrow[wv][0])[lane] = x;

    float m = fmaxf(fmaxf(x.x, x.y), fmaxf(x.z, x.w));
    #pragma unroll
    for (int off = 32; off; off >>= 1) m = fmaxf(m, __shfl_xor(m, off, 64));
    float s = __expf(x.x - m) + __expf(x.y - m) + __expf(x.z - m) + __expf(x.w - m);
    #pragma unroll
    for (int off = 32; off; off >>= 1) s += __shfl_xor(s, off, 64);
    float lse = m + __logf(s);

    int b = row / T;
    const int* tg = targets + (size_t)b * S;
    float* glr = gl + (size_t)row * VSZ;

    int c0 = 4 * lane;
    int l0 = tg[min(c0,     S - 1)];
    int l1 = tg[min(c0 + 1, S - 1)];
    int l2 = tg[min(c0 + 2, S - 1)];
    int l3 = tg[min(c0 + 3, S - 1)];
    float4 o;
    o.x = (ldsrow[wv][l0] - lse) * LOG2E;
    o.y = (ldsrow[wv][l1] - lse) * LOG2E;
    o.z = (ldsrow[wv][l2] - lse) * LOG2E;
    o.w = (ldsrow[wv][l3] - lse) * LOG2E;
    *(float4*)&glr[c0] = o;
    if (lane == 0) bl[row] = (x.x - lse) * LOG2E;
}

// ---------------------------------------------------------------------------
// Scan v4: 4 time steps per barrier, all state in NAMED registers (no
// arrays through lambdas -> no scratch). Thread i owns states 2i, 2i+1.
// Per period: publish {W8,W9} + own-column gather values (t,t+1,t+2) to
// LDS, lgkm-only barrier, read 8-state alpha halo + 6 halo gather values,
// 4 local micro-steps. Own column loaded with 4 coalesced scalar loads,
// prefetch distance 2 periods. Blank column staged in LDS (float4 reads).
// ---------------------------------------------------------------------------
__global__ __launch_bounds__(NTHR, 1) void ctc_scan4(const float* __restrict__ gl,
                                                     const float* __restrict__ bl,
                                                     const int* __restrict__ targets,
                                                     const int* __restrict__ llen_p,
                                                     const int* __restrict__ tlen_p,
                                                     float* __restrict__ out,
                                                     int T, int S) {
    const int b = blockIdx.x;
    const int i = threadIdx.x;
    const int len = llen_p[b];

    __shared__ __align__(16) float blankv[TCAP];
    __shared__ int    tgts[NTHR];
    __shared__ float2 exW[2][NTHR + 4];   // thread j's {W8,W9} at slot j+4
    __shared__ float4 exG[2][NTHR + 4];   // thread j's {g@t, g@t+1, g@t+2} at slot j+3
    __shared__ float  fin[2 * NTHR];

    const float* __restrict__ glb = gl + (size_t)b * T * VSZ;
    const float* __restrict__ blb = bl + (size_t)b * T;

    for (int t = i; t < len; t += NTHR) blankv[t] = blb[t];
    tgts[i] = targets[(size_t)b * S + min(i, S - 1)];
    if (i < 4) {                         // halo slots for threads < 0
        exW[0][i] = make_float2(NEG, NEG);
        exW[1][i] = make_float2(NEG, NEG);
        exG[0][i] = make_float4(0.f, 0.f, 0.f, 0.f);
        exG[1][i] = make_float4(0.f, 0.f, 0.f, 0.f);
    }
    __syncthreads();

    // skip flags: sk3=own odd state (slot 9), sk2=thread i-1 (slot 7), ...
    const bool sk0 = (i - 3 <= 0) ? true : (tgts[i - 3] != tgts[i - 4]);
    const bool sk1 = (i - 2 <= 0) ? true : (tgts[i - 2] != tgts[i - 3]);
    const bool sk2 = (i - 1 <= 0) ? true : (tgts[i - 1] != tgts[i - 2]);
    const bool sk3 = (i     <= 0) ? true : (tgts[i]     != tgts[i - 1]);

    float W[10];
    W[8] = (i == 0) ? 0.0f : NEG;
    W[9] = NEG;

    const int lm1 = len - 1;
    const float* pcol = glb + i;         // own column

    // own-column gather prefetch, distance 2 periods (clamped, always valid)
    float ga0 = pcol[0];
    float ga1 = pcol[(size_t)min(1, lm1) * VSZ];
    float ga2 = pcol[(size_t)min(2, lm1) * VSZ];
    float ga3 = pcol[(size_t)min(3, lm1) * VSZ];
    float gb0 = pcol[(size_t)min(4, lm1) * VSZ];
    float gb1 = pcol[(size_t)min(5, lm1) * VSZ];
    float gb2 = pcol[(size_t)min(6, lm1) * VSZ];
    float gb3 = pcol[(size_t)min(7, lm1) * VSZ];

    const int P = (len + 3) >> 2;

#define EV(m, BL)      W[m] = lae2b(W[m], W[m - 1]) + (BL)
#define OD(m, SK, GV)  W[m] = lae3b(W[m], W[m - 1], (SK) ? W[m - 2] : NEG) + (GV)

    for (int p = 0; p < P; ++p) {
        const int t   = 4 * p;
        const int par = p & 1;

        exW[par][i + 4] = make_float2(W[8], W[9]);
        exG[par][i + 3] = make_float4(ga0, ga1, ga2, 0.f);
        barrier_lgkm();

        // prefetch t+8..t+11 (consumed 2 periods from now)
        float gc0 = pcol[(size_t)min(t + 8,  lm1) * VSZ];
        float gc1 = pcol[(size_t)min(t + 9,  lm1) * VSZ];
        float gc2 = pcol[(size_t)min(t + 10, lm1) * VSZ];
        float gc3 = pcol[(size_t)min(t + 11, lm1) * VSZ];

        // alpha halo: states 2i-8 .. 2i-1 (threads i-4..i-1)
        float2 h0 = exW[par][i];
        float2 h1 = exW[par][i + 1];
        float2 h2 = exW[par][i + 2];
        float2 h3 = exW[par][i + 3];
        W[0] = h0.x; W[1] = h0.y; W[2] = h1.x; W[3] = h1.y;
        W[4] = h2.x; W[5] = h2.y; W[6] = h3.x; W[7] = h3.y;

        // gather halo: cols i-3 (t), i-2 (t,t+1), i-1 (t,t+1,t+2)
        float4 G3 = exG[par][i];
        float4 G2 = exG[par][i + 1];
        float4 G1 = exG[par][i + 2];

        float4 cb = *(const float4*)&blankv[t];

        // micro-steps (descending slot order: reads see old lower values)
        if (t < len) {
            OD(9, sk3, ga0); EV(8, cb.x); OD(7, sk2, G1.x); EV(6, cb.x);
            OD(5, sk1, G2.x); EV(4, cb.x); OD(3, sk0, G3.x); EV(2, cb.x);
        }
        if (t + 1 < len) {
            OD(9, sk3, ga1); EV(8, cb.y); OD(7, sk2, G1.y); EV(6, cb.y);
            OD(5, sk1, G2.y); EV(4, cb.y);
        }
        if (t + 2 < len) {
            OD(9, sk3, ga2); EV(8, cb.z); OD(7, sk2, G1.z); EV(6, cb.z);
        }
        if (t + 3 < len) {
            OD(9, sk3, ga3); EV(8, cb.w);
        }

        ga0 = gb0; ga1 = gb1; ga2 = gb2; ga3 = gb3;
        gb0 = gc0; gb1 = gc1; gb2 = gc2; gb3 = gc3;
    }
#undef EV
#undef OD

    fin[2 * i]     = W[8];
    fin[2 * i + 1] = W[9];
    __syncthreads();
    if (i == 0) {
        int tl = tlen_p[b];
        out[b] = -lae2b(fin[2 * tl - 1], fin[2 * tl]) * LN2;
    }
}

// ---------------------------------------------------------------------------
// Fallback path (R2) if workspace is too small for the gather matrix.
// ---------------------------------------------------------------------------
__global__ __launch_bounds__(256) void lse_kernel(const float* __restrict__ logits,
                                                  float* __restrict__ lse,
                                                  int nrows) {
    int row = blockIdx.x * 4 + (threadIdx.x >> 6);
    if (row >= nrows) return;
    int lane = threadIdx.x & 63;
    const float4* p = (const float4*)(logits + (size_t)row * VSZ);
    float4 x = p[lane];
    float m = fmaxf(fmaxf(x.x, x.y), fmaxf(x.z, x.w));
    #pragma unroll
    for (int off = 32; off; off >>= 1) m = fmaxf(m, __shfl_xor(m, off, 64));
    float s = __expf(x.x - m) + __expf(x.y - m) + __expf(x.z - m) + __expf(x.w - m);
    #pragma unroll
    for (int off = 32; off; off >>= 1) s += __shfl_xor(s, off, 64);
    if (lane == 0) lse[row] = m + __logf(s);
}

__device__ __forceinline__ float lae(float a, float b) {
    float mx = fmaxf(a, b);
    float mn = fminf(a, b);
    return mx + __logf(1.0f + __expf(mn - mx));
}

__global__ __launch_bounds__(NTHR, 1) void ctc_scan_fb(const float* __restrict__ logits,
                                                       const int* __restrict__ targets,
                                                       const int* __restrict__ llen_p,
                                                       const int* __restrict__ tlen_p,
                                                       const float* __restrict__ lse,
                                                       float* __restrict__ out,
                                                       int T, int S) {
    const int b = blockIdx.x;
    const int i = threadIdx.x;
    const int len = llen_p[b];

    __shared__ float blankv[TCAP];
    __shared__ float abuf[2][NTHR + 2];
    __shared__ float wsum[NTHR / 64];

    const float* __restrict__ lgb  = logits + (size_t)b * T * VSZ;
    const float* __restrict__ lseb = lse + (size_t)b * T;

    int  lab  = 0;
    bool skip = false;
    if (i < S) {
        lab = targets[b * S + i];
        int prev = (i >= 1) ? targets[b * S + i - 1] : -1;
        skip = (lab != prev);
    }
    for (int t = i; t < len; t += NTHR) blankv[t] = lgb[(size_t)t * VSZ];
    if (i < 2) abuf[i][0] = NEG;
    __syncthreads();

    float aEven = (i == 0) ? 0.0f : NEG;
    float aOdd  = NEG;
    const int lm1 = len - 1;
    float v0 = lgb[(size_t)lab];
    float v1 = lgb[(size_t)min(1, lm1) * VSZ + lab];
    float v2 = lgb[(size_t)min(2, lm1) * VSZ + lab];

    for (int t = 0; t < len; ++t) {
        float v3 = lgb[(size_t)min(t + 3, lm1) * VSZ + lab];
        float blv = blankv[t];
        abuf[t & 1][i + 1] = aOdd;
        barrier_lgkm();
        float nb = abuf[t & 1][i];
        float ne = lae(aEven, nb) + blv;
        float no = lae(lae(aOdd, aEven), skip ? nb : NEG) + v0;
        aEven = ne; aOdd = no;
        v0 = v1; v1 = v2; v2 = v3;
    }

    blankv[2 * i]     = aEven;
    blankv[2 * i + 1] = aOdd;
    float part = 0.f;
    for (int t = i; t < len; t += NTHR) part += lseb[t];
    #pragma unroll
    for (int off = 32; off; off >>= 1) part += __shfl_xor(part, off, 64);
    if ((i & 63) == 0) wsum[i >> 6] = part;
    __syncthreads();
    if (i == 0) {
        int tl = tlen_p[b];
        float s = wsum[0] + wsum[1] + wsum[2] + wsum[3];
        out[b] = s - lae(blankv[2 * tl - 1], blankv[2 * tl]);
    }
}

// ---------------------------------------------------------------------------
extern "C" void kernel_launch(void* const* d_in, const int* in_sizes, int n_in,
                              void* d_out, int out_size, void* d_ws, size_t ws_size,
                              hipStream_t stream) {
    const float* logits  = (const float*)d_in[0];
    const int*   targets = (const int*)d_in[1];
    const int*   llen    = (const int*)d_in[2];
    const int*   tlen    = (const int*)d_in[3];
    float*       out     = (float*)d_out;

    const int B = in_sizes[2];
    const int S = in_sizes[1] / B;
    const int T = in_sizes[0] / (B * VSZ);
    const int nrows = B * T;

    const size_t need = (size_t)nrows * VSZ * sizeof(float) + (size_t)nrows * sizeof(float);
    if (ws_size >= need) {
        float* gl = (float*)d_ws;                       // nrows * 256 floats
        float* bl = (float*)d_ws + (size_t)nrows * VSZ; // nrows floats
        prep_kernel<<<(nrows + 3) / 4, 256, 0, stream>>>(logits, targets, gl, bl, nrows, T, S);
        ctc_scan4<<<B, NTHR, 0, stream>>>(gl, bl, targets, llen, tlen, out, T, S);
    } else {
        float* lse = (float*)d_ws;                      // nrows floats
        lse_kernel<<<(nrows + 3) / 4, 256, 0, stream>>>(logits, lse, nrows);
        ctc_scan_fb<<<B, NTHR, 0, stream>>>(logits, targets, llen, tlen, lse, out, T, S);
    }
}